// Round 6
// baseline (94.758 us; speedup 1.0000x reference)
//
#include <hip/hip_runtime.h>
#include <stdint.h>
#include <math.h>

#define B_DIM 4096
#define H_DIM 1024
#define NI_DIM 4096
#define NQ_DIM 2048
#define K_DIM 5120   // H + NI
#define NKT 160      // K_DIM / 32

typedef __attribute__((ext_vector_type(8))) short short8;
typedef __attribute__((ext_vector_type(4))) float f32x4;

__device__ __forceinline__ unsigned short f2bf(float f) {
  unsigned u = __float_as_uint(f);
  u += 0x7FFFu + ((u >> 16) & 1u);  // round-to-nearest-even
  return (unsigned short)(u >> 16);
}
__device__ __forceinline__ float bf2f(unsigned short s) {
  return __uint_as_float(((unsigned)s) << 16);
}
__device__ __forceinline__ unsigned pkbf(float a, float b) {
  unsigned r;
  asm("v_cvt_pk_bf16_f32 %0, %1, %2" : "=v"(r) : "v"(a), "v"(b));
  return r;
}

__device__ __forceinline__ void gload_lds16(const void* g, void* l) {
  __builtin_amdgcn_global_load_lds(
      (__attribute__((address_space(1))) void*)(uintptr_t)g,
      (__attribute__((address_space(3))) void*)l, 16, 0, 0);
}

// fp32 -> bf16 cast into staged-tile layout, W only (1280 blocks):
//   dst chunk16 index = ((rowTile*NKT + kt)*4 + slot)*128 + row_in_tile
__global__ __launch_bounds__(256) void cast_w(
    const float* __restrict__ Wt, const float* __restrict__ Wx,
    short* __restrict__ Wc) {
  __shared__ __align__(16) short lds[4096];  // [4][128][8]
  const int bt = blockIdx.x;
  const int rowTile = bt / NKT;
  const int kt = bt % NKT;
  const float* src;
  long long srcBase;
  int cols;
  if (kt < 32) { src = Wt; cols = 1024; srcBase = (long long)kt * 32; }
  else         { src = Wx; cols = 4096; srcBase = (long long)(kt - 32) * 32; }
  const int tid = threadIdx.x;
#pragma unroll
  for (int half = 0; half < 2; ++half) {
    int c = tid + half * 256;          // cell: row r = c>>2, slot s = c&3
    int r = c >> 2, s = c & 3;
    long long sa = ((long long)(rowTile * 128 + r)) * cols + srcBase + s * 8;
    float4 v0 = *(const float4*)(src + sa);
    float4 v1 = *(const float4*)(src + sa + 4);
    short8 o;
    o[0] = (short)f2bf(v0.x); o[1] = (short)f2bf(v0.y);
    o[2] = (short)f2bf(v0.z); o[3] = (short)f2bf(v0.w);
    o[4] = (short)f2bf(v1.x); o[5] = (short)f2bf(v1.y);
    o[6] = (short)f2bf(v1.z); o[7] = (short)f2bf(v1.w);
    *(short8*)(&lds[(s * 128 + r) * 8]) = o;
  }
  __syncthreads();
  short* dtile = Wc + (((long long)rowTile * NKT + kt) * 512) * 8;
#pragma unroll
  for (int half = 0; half < 2; ++half) {
    int c = tid + half * 256;
    *(short8*)(dtile + c * 8) = *(const short8*)(&lds[c * 8]);
  }
}

// LDS byte-swizzle for the epilogue transpose buffer [col][row] bf16.
__device__ __forceinline__ int ep_swz(int col, int rw) {
  int byte = col * 256 + rw * 2;
  byte ^= ((col ^ (col >> 3)) & 7) << 4;   // spread banks, keeps 8B align
  return byte;
}

// Split-K GEMM. A: register-staged fp32 (state/inputX read directly),
// converted via v_cvt_pk_bf16_f32, ds_write'd into the proven conflict-free
// [slot][row] LDS layout. B: global_load_lds dbuf from staged-tile Wc.
// Core ds_read/MFMA loop identical to R3/R5 (925 TF verified).
__global__ __launch_bounds__(256, 4) void gemm_splitk(
    const float* __restrict__ state, const float* __restrict__ inputX,
    const short* __restrict__ Wc, short* __restrict__ P, int ntk) {
  __shared__ __align__(16) short SH[16384];  // As dbuf 16KB | Bs dbuf 16KB
  const int tid = threadIdx.x;
  const int lane = tid & 63;
  const int wid = tid >> 6;
  const int wm = wid >> 1, wn = wid & 1;
  const int fr = lane & 15, fq = lane >> 4;

  const int nwg = gridDim.x;
  const int orig = blockIdx.x;
  const int cpx = nwg >> 3;
  const int swz = (orig & 7) * cpx + (orig >> 3);
  const int bz = swz >> 8;
  const int bm = (swz >> 3) & 31;
  const int bn = swz & 7;
  const int kt0 = bz * ntk;

  // A reg-staging: thread c owns row r = c>>1, k-half h = c&1 (16 floats)
  const int r = tid >> 1, hh = tid & 1;
  const float* qS = state  + (long long)(bm * 128 + r) * 1024 + hh * 16;
  const float* qX = inputX + (long long)(bm * 128 + r) * 4096 + hh * 16;

  const int c0 = tid, c1 = tid + 256;
  const short* gB = Wc + (((long long)bn * NKT + kt0) << 12);  // *4096 shorts

  f32x4 acc[4][4] = {};
  float4 rA0, rA1, rA2, rA3;

  // prologue: A(0) -> regs -> cvt -> As[0]; B(0) -> Bs[0]
  {
    int ktg = kt0;
    const float* q = (ktg < 32) ? (qS + ktg * 32) : (qX + (ktg - 32) * 32);
    rA0 = *(const float4*)(q);
    rA1 = *(const float4*)(q + 4);
    rA2 = *(const float4*)(q + 8);
    rA3 = *(const float4*)(q + 12);
    gload_lds16(gB + c0 * 8, &SH[8192 + c0 * 8]);
    gload_lds16(gB + c1 * 8, &SH[8192 + c1 * 8]);
    uint4 w0, w1;
    w0.x = pkbf(rA0.x, rA0.y); w0.y = pkbf(rA0.z, rA0.w);
    w0.z = pkbf(rA1.x, rA1.y); w0.w = pkbf(rA1.z, rA1.w);
    w1.x = pkbf(rA2.x, rA2.y); w1.y = pkbf(rA2.z, rA2.w);
    w1.z = pkbf(rA3.x, rA3.y); w1.w = pkbf(rA3.z, rA3.w);
    *(uint4*)(&SH[((2 * hh) * 128 + r) * 8]) = w0;
    *(uint4*)(&SH[((2 * hh + 1) * 128 + r) * 8]) = w1;
  }
  __syncthreads();

  int cur = 0;
  for (int t = 0; t < ntk; ++t) {
    if (t + 1 < ntk) {
      // issue A(t+1) fp32 loads early (consumed late this iter)
      int ktg = kt0 + t + 1;
      const float* q = (ktg < 32) ? (qS + ktg * 32) : (qX + (ktg - 32) * 32);
      rA0 = *(const float4*)(q);
      rA1 = *(const float4*)(q + 4);
      rA2 = *(const float4*)(q + 8);
      rA3 = *(const float4*)(q + 12);
      // B(t+1) -> Bs[cur^1]
      const short* nB = gB + (long long)(t + 1) * 4096;
      short* lB = &SH[8192 + (cur ^ 1) * 4096];
      gload_lds16(nB + c0 * 8, lB + c0 * 8);
      gload_lds16(nB + c1 * 8, lB + c1 * 8);
    }
    const short* a_base = &SH[cur * 4096];
    const short* b_base = &SH[8192 + cur * 4096];
    short8 av[4], bv[4];
#pragma unroll
    for (int i = 0; i < 4; i++) {
      // [slot=fq][row = w*64 + i*16 + fr][8] -> conflict-free granules
      av[i] = *(const short8*)(a_base + (fq * 128 + wm * 64 + i * 16 + fr) * 8);
      bv[i] = *(const short8*)(b_base + (fq * 128 + wn * 64 + i * 16 + fr) * 8);
    }
#pragma unroll
    for (int mi = 0; mi < 4; mi++)
#pragma unroll
      for (int ni = 0; ni < 4; ni++)
        acc[mi][ni] = __builtin_amdgcn_mfma_f32_16x16x32_bf16(
            av[mi], bv[ni], acc[mi][ni], 0, 0, 0);
    if (t + 1 < ntk) {
      // cvt A(t+1) and place into As[cur^1] (WAR-safe: last read was t-1,
      // protected by the barrier at end of iter t-1)
      short* lA = &SH[(cur ^ 1) * 4096];
      uint4 w0, w1;
      w0.x = pkbf(rA0.x, rA0.y); w0.y = pkbf(rA0.z, rA0.w);
      w0.z = pkbf(rA1.x, rA1.y); w0.w = pkbf(rA1.z, rA1.w);
      w1.x = pkbf(rA2.x, rA2.y); w1.y = pkbf(rA2.z, rA2.w);
      w1.z = pkbf(rA3.x, rA3.y); w1.w = pkbf(rA3.z, rA3.w);
      *(uint4*)(lA + ((2 * hh) * 128 + r) * 8) = w0;
      *(uint4*)(lA + ((2 * hh + 1) * 128 + r) * 8) = w1;
    }
    __syncthreads();
    cur ^= 1;
  }

  // ---- epilogue: bf16 transpose through LDS, coalesced global stores ----
#pragma unroll
  for (int ni = 0; ni < 4; ni++) {
    int col = wn * 64 + ni * 16 + fr;
#pragma unroll
    for (int mi = 0; mi < 4; mi++) {
      int rw = wm * 64 + mi * 16 + fq * 4;
      unsigned lo = (unsigned)f2bf(acc[mi][ni][0]) |
                    ((unsigned)f2bf(acc[mi][ni][1]) << 16);
      unsigned hi = (unsigned)f2bf(acc[mi][ni][2]) |
                    ((unsigned)f2bf(acc[mi][ni][3]) << 16);
      uint2 pk; pk.x = lo; pk.y = hi;
      *(uint2*)((char*)SH + ep_swz(col, rw)) = pk;
    }
  }
  __syncthreads();
  short* Pp = P + (long long)bz * B_DIM * H_DIM;
#pragma unroll
  for (int h = 0; h < 8; ++h) {
    int chunk = tid + h * 256;        // 2048 chunks = 128 rows x 16 colblocks
    int rr = chunk >> 4;
    int j = chunk & 15;
    short8 o;
#pragma unroll
    for (int k = 0; k < 8; ++k) {
      o[k] = *(const short*)((char*)SH + ep_swz(j * 8 + k, rr));
    }
    *(short8*)(Pp + (long long)(bm * 128 + rr) * H_DIM + bn * 128 + j * 8) = o;
  }
}

// Fused: per-row split-K reduce + bias + tanh + hidden write + one-hot
// select + Wy dot + sigmoid + BCE term.
__global__ __launch_bounds__(256) void fuse_row(
    const short* __restrict__ P, const float* __restrict__ bt,
    const float* __restrict__ bx, const float* __restrict__ Y,
    const float* __restrict__ truth, const float* __restrict__ Wy,
    const float* __restrict__ by, float* __restrict__ predOut,
    float* __restrict__ hidden, float* __restrict__ bce, int S) {
  const int b = blockIdx.x;
  const int tid = threadIdx.x;
  __shared__ int s_cnt;
  __shared__ int s_idx[8];
  __shared__ float s_val[8];
  __shared__ float s_red[4];
  if (tid == 0) s_cnt = 0;

  const int c = tid * 4;
  float s0 = 0.f, s1 = 0.f, s2 = 0.f, s3 = 0.f;
  for (int z = 0; z < S; ++z) {
    const short* Pr = P + ((long long)z * B_DIM + b) * H_DIM + c;
    uint2 u = *(const uint2*)Pr;
    s0 += bf2f((unsigned short)(u.x & 0xffff));
    s1 += bf2f((unsigned short)(u.x >> 16));
    s2 += bf2f((unsigned short)(u.y & 0xffff));
    s3 += bf2f((unsigned short)(u.y >> 16));
  }
  float4 bt4 = *(const float4*)(bt + c);
  float4 bx4 = *(const float4*)(bx + c);
  float h0 = tanhf(s0 + bt4.x + bx4.x);
  float h1 = tanhf(s1 + bt4.y + bx4.y);
  float h2 = tanhf(s2 + bt4.z + bx4.z);
  float h3 = tanhf(s3 + bt4.w + bx4.w);
  float* Hr = hidden + (long long)b * H_DIM + c;  // base unaligned -> scalar
  Hr[0] = h0; Hr[1] = h1; Hr[2] = h2; Hr[3] = h3;

  __syncthreads();  // covers s_cnt init
  const float4* Yr = (const float4*)(Y + (long long)b * NQ_DIM);
#pragma unroll
  for (int hh = 0; hh < NQ_DIM / 4 / 256; ++hh) {
    int j = tid + hh * 256;
    float4 v = Yr[j];
    if (v.x != 0.0f) { int p = atomicAdd(&s_cnt, 1); if (p < 8) { s_idx[p] = 4 * j;     s_val[p] = v.x; } }
    if (v.y != 0.0f) { int p = atomicAdd(&s_cnt, 1); if (p < 8) { s_idx[p] = 4 * j + 1; s_val[p] = v.y; } }
    if (v.z != 0.0f) { int p = atomicAdd(&s_cnt, 1); if (p < 8) { s_idx[p] = 4 * j + 2; s_val[p] = v.z; } }
    if (v.w != 0.0f) { int p = atomicAdd(&s_cnt, 1); if (p < 8) { s_idx[p] = 4 * j + 3; s_val[p] = v.w; } }
  }
  __syncthreads();
  int cnt = s_cnt < 8 ? s_cnt : 8;
  float predv = 0.0f;
  for (int it = 0; it < cnt; ++it) {
    int q = s_idx[it];
    float4 w = *(const float4*)(Wy + (long long)q * H_DIM + c);
    float part = h0 * w.x + h1 * w.y + h2 * w.z + h3 * w.w;
#pragma unroll
    for (int off = 32; off > 0; off >>= 1) part += __shfl_down(part, off, 64);
    if ((tid & 63) == 0) s_red[tid >> 6] = part;
    __syncthreads();
    if (tid == 0) {
      float z = s_red[0] + s_red[1] + s_red[2] + s_red[3] + by[q];
      float p = 1.0f / (1.0f + expf(-z));
      predv += s_val[it] * p;
    }
    __syncthreads();
  }
  if (tid == 0) {
    predOut[b] = predv;
    float t = truth[b];
    float lp = fmaxf(logf(predv), -100.0f);
    float l1p = fmaxf(log1pf(-predv), -100.0f);
    bce[b] = -(t * lp + (1.0f - t) * l1p);
  }
}

__global__ __launch_bounds__(256) void reduce_err(
    const float* __restrict__ bce, float* __restrict__ errOut) {
  float s = 0.0f;
  for (int i = threadIdx.x; i < B_DIM; i += 256) s += bce[i];
#pragma unroll
  for (int off = 32; off > 0; off >>= 1) s += __shfl_down(s, off, 64);
  __shared__ float red[4];
  if ((threadIdx.x & 63) == 0) red[threadIdx.x >> 6] = s;
  __syncthreads();
  if (threadIdx.x == 0) errOut[0] = red[0] + red[1] + red[2] + red[3];
}

extern "C" void kernel_launch(void* const* d_in, const int* in_sizes, int n_in,
                              void* d_out, int out_size, void* d_ws, size_t ws_size,
                              hipStream_t stream) {
  (void)in_sizes; (void)n_in; (void)out_size;
  const float* state  = (const float*)d_in[0];
  const float* inputX = (const float*)d_in[1];
  const float* inputY = (const float*)d_in[2];
  const float* truth  = (const float*)d_in[3];
  const float* W_t    = (const float*)d_in[4];
  const float* b_t    = (const float*)d_in[5];
  const float* W_x    = (const float*)d_in[6];
  const float* b_x    = (const float*)d_in[7];
  const float* W_y    = (const float*)d_in[8];
  const float* b_y    = (const float*)d_in[9];

  const size_t WC_B = (size_t)H_DIM * K_DIM * 2;   // 10.5 MB
  const size_t PART = (size_t)B_DIM * H_DIM * 2;   // 8.4 MB per split (bf16)

  int S = 1;
  if (ws_size >= WC_B + 4 * PART + 16384) S = 4;
  else if (ws_size >= WC_B + 2 * PART + 16384) S = 2;

  short* Wc = (short*)d_ws;
  short* P  = (short*)((char*)d_ws + WC_B);
  float* bce = (float*)((char*)d_ws + WC_B + (size_t)S * PART);

  float* predOut = (float*)d_out;             // [0 .. 4095]
  float* errOut  = predOut + B_DIM;           // [4096]
  float* hidden  = predOut + B_DIM + 1;       // [4097 ..]

  cast_w<<<(H_DIM / 128) * NKT, 256, 0, stream>>>(W_t, W_x, Wc);

  gemm_splitk<<<256 * S, 256, 0, stream>>>(state, inputX, Wc, P, NKT / S);

  fuse_row<<<B_DIM, 256, 0, stream>>>(P, b_t, b_x, inputY, truth, W_y, b_y,
                                      predOut, hidden, bce, S);
  reduce_err<<<1, 256, 0, stream>>>(bce, errOut);
}

// Round 7
// 94.138 us; speedup vs baseline: 1.0066x; 1.0066x over previous
//
#include <hip/hip_runtime.h>
#include <stdint.h>
#include <math.h>

#define B_DIM 4096
#define H_DIM 1024
#define NI_DIM 4096
#define NQ_DIM 2048
#define K_DIM 5120   // H + NI
#define NKT 160      // K_DIM / 32

typedef __attribute__((ext_vector_type(8))) short short8;
typedef __attribute__((ext_vector_type(4))) float f32x4;

__device__ __forceinline__ unsigned short f2bf(float f) {
  unsigned u = __float_as_uint(f);
  u += 0x7FFFu + ((u >> 16) & 1u);  // round-to-nearest-even
  return (unsigned short)(u >> 16);
}
__device__ __forceinline__ float bf2f(unsigned short s) {
  return __uint_as_float(((unsigned)s) << 16);
}
__device__ __forceinline__ unsigned pkbf(float a, float b) {
  unsigned r;
  asm("v_cvt_pk_bf16_f32 %0, %1, %2" : "=v"(r) : "v"(a), "v"(b));
  return r;
}

__device__ __forceinline__ void gload_lds16(const void* g, void* l) {
  __builtin_amdgcn_global_load_lds(
      (__attribute__((address_space(1))) void*)(uintptr_t)g,
      (__attribute__((address_space(3))) void*)l, 16, 0, 0);
}

// fp32 -> bf16 cast into staged-tile layout, streaming-friendly version.
// Block = (rowTile, ktb): 128 rows x 256 fp32 cols = 8 consecutive kt-tiles.
// Reads: each wave reads ONE row's 1KB contiguously per instruction.
// LDS bounce (64KB) with XOR chunk swizzle p = l ^ ((l>>7)&7) -- bank-exact
// conflict-free for both 8B writes and 16B reads.
// Writes: one contiguous 64KB block (staged layout is (rowTile,kt)-major).
__global__ __launch_bounds__(256) void cast_v3(
    const float* __restrict__ X0, const float* __restrict__ X1,
    const float* __restrict__ W0, const float* __restrict__ W1,
    short* __restrict__ Xc, short* __restrict__ Wc) {
  __shared__ __align__(16) short lds[32768];  // 4096 chunks x 8 shorts
  int bt = blockIdx.x;
  const float *s0, *s1;
  short* dst;
  if (bt < (B_DIM / 128) * (NKT / 8)) { s0 = X0; s1 = X1; dst = Xc; }
  else { bt -= (B_DIM / 128) * (NKT / 8); s0 = W0; s1 = W1; dst = Wc; }
  const int rowTile = bt / (NKT / 8);
  const int ktb = bt % (NKT / 8);
  const int K0 = ktb * 8;
  const float* src;
  int cols, colBase;
  if (K0 < 32) { src = s0; cols = 1024; colBase = K0 * 32; }
  else         { src = s1; cols = 4096; colBase = (K0 - 32) * 32; }
  const int tid = threadIdx.x;
  const int rsub = tid >> 6;   // wave id -> row offset in group of 4
  const int kc = tid & 63;     // float4 column chunk
#pragma unroll 4
  for (int i = 0; i < 32; ++i) {
    int r = i * 4 + rsub;
    float4 v = *(const float4*)(src +
        (long long)(rowTile * 128 + r) * cols + colBase + kc * 4);
    uint2 o;
    o.x = pkbf(v.x, v.y);
    o.y = pkbf(v.z, v.w);
    int l = (kc >> 1) * 128 + r;          // logical chunk
    int p = l ^ ((kc >> 1) & 7);          // physical (bank-spread)
    *(uint2*)(&lds[p * 8 + (kc & 1) * 4]) = o;
  }
  __syncthreads();
  short* dbase = dst + ((long long)rowTile * NKT + K0) * 4096;
#pragma unroll
  for (int i = 0; i < 16; ++i) {
    int c = tid + i * 256;
    int p = c ^ ((c >> 7) & 7);
    *(short8*)(dbase + c * 8) = *(const short8*)(&lds[p * 8]);
  }
}

// LDS byte-swizzle for the epilogue transpose buffer [col][row] bf16.
__device__ __forceinline__ int ep_swz(int col, int rw) {
  int byte = col * 256 + rw * 2;
  byte ^= ((col ^ (col >> 3)) & 7) << 4;   // spread banks, keeps 8B align
  return byte;
}

// Split-K GEMM (R5-proven: 46.5us, MfmaUtil 37.7%, conflicts epilogue-only).
// 128x128 tile, BK=32, 4 waves (2x2), dbuf LDS via global_load_lds w=16 on
// staged-tile Xc/Wc; bf16 partials via LDS-transposed coalesced epilogue.
__global__ __launch_bounds__(256, 4) void gemm_splitk(
    const short* __restrict__ Xc, const short* __restrict__ Wc,
    short* __restrict__ P, int ntk) {
  __shared__ __align__(16) short SH[16384];  // A dbuf 16KB | B dbuf 16KB
  const int tid = threadIdx.x;
  const int lane = tid & 63;
  const int wid = tid >> 6;
  const int wm = wid >> 1, wn = wid & 1;
  const int fr = lane & 15, fq = lane >> 4;

  const int nwg = gridDim.x;
  const int orig = blockIdx.x;
  const int cpx = nwg >> 3;
  const int swz = (orig & 7) * cpx + (orig >> 3);
  const int bz = swz >> 8;
  const int bm = (swz >> 3) & 31;
  const int bn = swz & 7;
  const int kt0 = bz * ntk;

  const int c0 = tid, c1 = tid + 256;
  const short* gA = Xc + (((long long)bm * NKT + kt0) << 12);  // *4096 shorts
  const short* gB = Wc + (((long long)bn * NKT + kt0) << 12);

  f32x4 acc[4][4] = {};

  gload_lds16(gA + c0 * 8, &SH[c0 * 8]);
  gload_lds16(gA + c1 * 8, &SH[c1 * 8]);
  gload_lds16(gB + c0 * 8, &SH[8192 + c0 * 8]);
  gload_lds16(gB + c1 * 8, &SH[8192 + c1 * 8]);
  __syncthreads();

  int cur = 0;
  for (int t = 0; t < ntk; ++t) {
    if (t + 1 < ntk) {
      const short* nA = gA + (long long)(t + 1) * 4096;
      const short* nB = gB + (long long)(t + 1) * 4096;
      short* lA = &SH[(cur ^ 1) * 4096];
      short* lB = &SH[8192 + (cur ^ 1) * 4096];
      gload_lds16(nA + c0 * 8, lA + c0 * 8);
      gload_lds16(nA + c1 * 8, lA + c1 * 8);
      gload_lds16(nB + c0 * 8, lB + c0 * 8);
      gload_lds16(nB + c1 * 8, lB + c1 * 8);
    }
    const short* a_base = &SH[cur * 4096];
    const short* b_base = &SH[8192 + cur * 4096];
    short8 av[4], bv[4];
#pragma unroll
    for (int i = 0; i < 4; i++) {
      // [slot=fq][row = w*64 + i*16 + fr][8] -> conflict-free granules
      av[i] = *(const short8*)(a_base + (fq * 128 + wm * 64 + i * 16 + fr) * 8);
      bv[i] = *(const short8*)(b_base + (fq * 128 + wn * 64 + i * 16 + fr) * 8);
    }
#pragma unroll
    for (int mi = 0; mi < 4; mi++)
#pragma unroll
      for (int ni = 0; ni < 4; ni++)
        acc[mi][ni] = __builtin_amdgcn_mfma_f32_16x16x32_bf16(
            av[mi], bv[ni], acc[mi][ni], 0, 0, 0);
    __syncthreads();
    cur ^= 1;
  }

  // ---- epilogue: bf16 transpose through LDS, coalesced global stores ----
#pragma unroll
  for (int ni = 0; ni < 4; ni++) {
    int col = wn * 64 + ni * 16 + fr;
#pragma unroll
    for (int mi = 0; mi < 4; mi++) {
      int rw = wm * 64 + mi * 16 + fq * 4;
      unsigned lo = (unsigned)f2bf(acc[mi][ni][0]) |
                    ((unsigned)f2bf(acc[mi][ni][1]) << 16);
      unsigned hi = (unsigned)f2bf(acc[mi][ni][2]) |
                    ((unsigned)f2bf(acc[mi][ni][3]) << 16);
      uint2 pk; pk.x = lo; pk.y = hi;
      *(uint2*)((char*)SH + ep_swz(col, rw)) = pk;
    }
  }
  __syncthreads();
  short* Pp = P + (long long)bz * B_DIM * H_DIM;
#pragma unroll
  for (int h = 0; h < 8; ++h) {
    int chunk = tid + h * 256;        // 2048 chunks = 128 rows x 16 colblocks
    int rr = chunk >> 4;
    int j = chunk & 15;
    short8 o;
#pragma unroll
    for (int k = 0; k < 8; ++k) {
      o[k] = *(const short*)((char*)SH + ep_swz(j * 8 + k, rr));
    }
    *(short8*)(Pp + (long long)(bm * 128 + rr) * H_DIM + bn * 128 + j * 8) = o;
  }
}

// Fused: per-row split-K reduce + bias + tanh + hidden write + one-hot
// select + Wy dot + sigmoid + BCE term.
__global__ __launch_bounds__(256) void fuse_row(
    const short* __restrict__ P, const float* __restrict__ bt,
    const float* __restrict__ bx, const float* __restrict__ Y,
    const float* __restrict__ truth, const float* __restrict__ Wy,
    const float* __restrict__ by, float* __restrict__ predOut,
    float* __restrict__ hidden, float* __restrict__ bce, int S) {
  const int b = blockIdx.x;
  const int tid = threadIdx.x;
  __shared__ int s_cnt;
  __shared__ int s_idx[8];
  __shared__ float s_val[8];
  __shared__ float s_red[4];
  if (tid == 0) s_cnt = 0;

  const int c = tid * 4;
  float s0 = 0.f, s1 = 0.f, s2 = 0.f, s3 = 0.f;
  for (int z = 0; z < S; ++z) {
    const short* Pr = P + ((long long)z * B_DIM + b) * H_DIM + c;
    uint2 u = *(const uint2*)Pr;
    s0 += bf2f((unsigned short)(u.x & 0xffff));
    s1 += bf2f((unsigned short)(u.x >> 16));
    s2 += bf2f((unsigned short)(u.y & 0xffff));
    s3 += bf2f((unsigned short)(u.y >> 16));
  }
  float4 bt4 = *(const float4*)(bt + c);
  float4 bx4 = *(const float4*)(bx + c);
  float h0 = tanhf(s0 + bt4.x + bx4.x);
  float h1 = tanhf(s1 + bt4.y + bx4.y);
  float h2 = tanhf(s2 + bt4.z + bx4.z);
  float h3 = tanhf(s3 + bt4.w + bx4.w);
  float* Hr = hidden + (long long)b * H_DIM + c;  // base unaligned -> scalar
  Hr[0] = h0; Hr[1] = h1; Hr[2] = h2; Hr[3] = h3;

  __syncthreads();  // covers s_cnt init
  const float4* Yr = (const float4*)(Y + (long long)b * NQ_DIM);
#pragma unroll
  for (int hh = 0; hh < NQ_DIM / 4 / 256; ++hh) {
    int j = tid + hh * 256;
    float4 v = Yr[j];
    if (v.x != 0.0f) { int p = atomicAdd(&s_cnt, 1); if (p < 8) { s_idx[p] = 4 * j;     s_val[p] = v.x; } }
    if (v.y != 0.0f) { int p = atomicAdd(&s_cnt, 1); if (p < 8) { s_idx[p] = 4 * j + 1; s_val[p] = v.y; } }
    if (v.z != 0.0f) { int p = atomicAdd(&s_cnt, 1); if (p < 8) { s_idx[p] = 4 * j + 2; s_val[p] = v.z; } }
    if (v.w != 0.0f) { int p = atomicAdd(&s_cnt, 1); if (p < 8) { s_idx[p] = 4 * j + 3; s_val[p] = v.w; } }
  }
  __syncthreads();
  int cnt = s_cnt < 8 ? s_cnt : 8;
  float predv = 0.0f;
  for (int it = 0; it < cnt; ++it) {
    int q = s_idx[it];
    float4 w = *(const float4*)(Wy + (long long)q * H_DIM + c);
    float part = h0 * w.x + h1 * w.y + h2 * w.z + h3 * w.w;
#pragma unroll
    for (int off = 32; off > 0; off >>= 1) part += __shfl_down(part, off, 64);
    if ((tid & 63) == 0) s_red[tid >> 6] = part;
    __syncthreads();
    if (tid == 0) {
      float z = s_red[0] + s_red[1] + s_red[2] + s_red[3] + by[q];
      float p = 1.0f / (1.0f + expf(-z));
      predv += s_val[it] * p;
    }
    __syncthreads();
  }
  if (tid == 0) {
    predOut[b] = predv;
    float t = truth[b];
    float lp = fmaxf(logf(predv), -100.0f);
    float l1p = fmaxf(log1pf(-predv), -100.0f);
    bce[b] = -(t * lp + (1.0f - t) * l1p);
  }
}

__global__ __launch_bounds__(256) void reduce_err(
    const float* __restrict__ bce, float* __restrict__ errOut) {
  float s = 0.0f;
  for (int i = threadIdx.x; i < B_DIM; i += 256) s += bce[i];
#pragma unroll
  for (int off = 32; off > 0; off >>= 1) s += __shfl_down(s, off, 64);
  __shared__ float red[4];
  if ((threadIdx.x & 63) == 0) red[threadIdx.x >> 6] = s;
  __syncthreads();
  if (threadIdx.x == 0) errOut[0] = red[0] + red[1] + red[2] + red[3];
}

extern "C" void kernel_launch(void* const* d_in, const int* in_sizes, int n_in,
                              void* d_out, int out_size, void* d_ws, size_t ws_size,
                              hipStream_t stream) {
  (void)in_sizes; (void)n_in; (void)out_size;
  const float* state  = (const float*)d_in[0];
  const float* inputX = (const float*)d_in[1];
  const float* inputY = (const float*)d_in[2];
  const float* truth  = (const float*)d_in[3];
  const float* W_t    = (const float*)d_in[4];
  const float* b_t    = (const float*)d_in[5];
  const float* W_x    = (const float*)d_in[6];
  const float* b_x    = (const float*)d_in[7];
  const float* W_y    = (const float*)d_in[8];
  const float* b_y    = (const float*)d_in[9];

  const size_t XC_B = (size_t)B_DIM * K_DIM * 2;   // 41.9 MB
  const size_t WC_B = (size_t)H_DIM * K_DIM * 2;   // 10.5 MB
  const size_t PART = (size_t)B_DIM * H_DIM * 2;   // 8.4 MB per split (bf16)

  int S = 1;
  if (ws_size >= XC_B + WC_B + 4 * PART + 16384) S = 4;
  else if (ws_size >= XC_B + WC_B + 2 * PART + 16384) S = 2;

  short* Xc = (short*)d_ws;
  short* Wc = (short*)((char*)d_ws + XC_B);
  short* P  = (short*)((char*)d_ws + XC_B + WC_B);
  float* bce = (float*)((char*)d_ws + XC_B + WC_B + (size_t)S * PART);

  float* predOut = (float*)d_out;             // [0 .. 4095]
  float* errOut  = predOut + B_DIM;           // [4096]
  float* hidden  = predOut + B_DIM + 1;       // [4097 ..]

  cast_v3<<<(B_DIM / 128 + H_DIM / 128) * (NKT / 8), 256, 0, stream>>>(
      state, inputX, W_t, W_x, Xc, Wc);

  gemm_splitk<<<256 * S, 256, 0, stream>>>(Xc, Wc, P, NKT / S);

  fuse_row<<<B_DIM, 256, 0, stream>>>(P, b_t, b_x, inputY, truth, W_y, b_y,
                                      predOut, hidden, bce, S);
  reduce_err<<<1, 256, 0, stream>>>(bce, errOut);
}